// Round 1
// baseline (3241.334 us; speedup 1.0000x reference)
//
#include <hip/hip_runtime.h>

#define S_LEN 2048
#define EMB   2048
#define NH    16
#define HD    128
#define NBH   32     // B*H
#define MTOT  4096   // B*S

// ============================================================================
// GEMM pattern: 128x128 block tile, 256 threads, 8x8 register fragment,
// K-tile 16, A stored transposed [k][row] in LDS (stride 132 = 16B aligned,
// pad breaks power-of-2 bank strides).
// ============================================================================

__global__ __launch_bounds__(256) void gemm_qkv_kernel(
    const float* __restrict__ X,
    const float* __restrict__ Wq, const float* __restrict__ Wk,
    const float* __restrict__ Wv,
    float* __restrict__ Qo, float* __restrict__ Ko, float* __restrict__ Vo)
{
    __shared__ __attribute__((aligned(16))) float Xs[16][132];
    __shared__ __attribute__((aligned(16))) float Ws[16][132];
    const int t = threadIdx.x;
    const int tx = t & 15, ty = t >> 4;
    const int n0 = blockIdx.x * 128;
    const int m0 = blockIdx.y * 128;
    const int wsel = blockIdx.z;
    const float* __restrict__ W = (wsel == 0) ? Wq : (wsel == 1) ? Wk : Wv;
    float* __restrict__ O = (wsel == 0) ? Qo : (wsel == 1) ? Ko : Vo;

    const int xr0  = t >> 2;          // 0..63 (+64 for second load)
    const int xkq  = (t & 3) << 2;    // 0,4,8,12
    const int wkk0 = t >> 5;          // 0..7 (+8 for second load)
    const int wnq  = (t & 31) << 2;   // 0..124

    float acc[8][8] = {};

    for (int k0 = 0; k0 < EMB; k0 += 16) {
        float4 xv0 = *(const float4*)&X[(size_t)(m0 + xr0) * EMB + k0 + xkq];
        float4 xv1 = *(const float4*)&X[(size_t)(m0 + xr0 + 64) * EMB + k0 + xkq];
        float4 wv0 = *(const float4*)&W[(size_t)(k0 + wkk0) * EMB + n0 + wnq];
        float4 wv1 = *(const float4*)&W[(size_t)(k0 + wkk0 + 8) * EMB + n0 + wnq];
        __syncthreads();
        {
            float xa0[4] = {xv0.x, xv0.y, xv0.z, xv0.w};
            float xa1[4] = {xv1.x, xv1.y, xv1.z, xv1.w};
#pragma unroll
            for (int j = 0; j < 4; ++j) {
                Xs[xkq + j][xr0]      = xa0[j];
                Xs[xkq + j][xr0 + 64] = xa1[j];
            }
            *(float4*)&Ws[wkk0][wnq]     = wv0;
            *(float4*)&Ws[wkk0 + 8][wnq] = wv1;
        }
        __syncthreads();
#pragma unroll
        for (int kk = 0; kk < 16; ++kk) {
            float a[8], b[8];
            *(float4*)&a[0] = *(const float4*)&Xs[kk][ty * 8];
            *(float4*)&a[4] = *(const float4*)&Xs[kk][ty * 8 + 4];
            *(float4*)&b[0] = *(const float4*)&Ws[kk][tx * 8];
            *(float4*)&b[4] = *(const float4*)&Ws[kk][tx * 8 + 4];
#pragma unroll
            for (int i = 0; i < 8; ++i)
#pragma unroll
                for (int j = 0; j < 8; ++j)
                    acc[i][j] = fmaf(a[i], b[j], acc[i][j]);
        }
    }

    // write to [B,H,S,D]; 8-col chunk never straddles a head (tx*8 <= 120)
    const int nb0 = n0 + tx * 8;
    const int h  = nb0 >> 7;
    const int d0 = nb0 & 127;
#pragma unroll
    for (int i = 0; i < 8; ++i) {
        const int m  = m0 + ty * 8 + i;
        const int bb = m >> 11;
        const int s  = m & 2047;
        float* dst = &O[(((size_t)(bb * NH + h) * S_LEN) + s) * HD + d0];
        *(float4*)&dst[0] = make_float4(acc[i][0], acc[i][1], acc[i][2], acc[i][3]);
        *(float4*)&dst[4] = make_float4(acc[i][4], acc[i][5], acc[i][6], acc[i][7]);
    }
}

__global__ __launch_bounds__(256) void gemm_out_kernel(
    const float* __restrict__ X, const float* __restrict__ W,
    const float* __restrict__ bias, float* __restrict__ Out)
{
    __shared__ __attribute__((aligned(16))) float Xs[16][132];
    __shared__ __attribute__((aligned(16))) float Ws[16][132];
    const int t = threadIdx.x;
    const int tx = t & 15, ty = t >> 4;
    const int n0 = blockIdx.x * 128;
    const int m0 = blockIdx.y * 128;

    const int xr0  = t >> 2;
    const int xkq  = (t & 3) << 2;
    const int wkk0 = t >> 5;
    const int wnq  = (t & 31) << 2;

    float acc[8][8] = {};

    for (int k0 = 0; k0 < EMB; k0 += 16) {
        float4 xv0 = *(const float4*)&X[(size_t)(m0 + xr0) * EMB + k0 + xkq];
        float4 xv1 = *(const float4*)&X[(size_t)(m0 + xr0 + 64) * EMB + k0 + xkq];
        float4 wv0 = *(const float4*)&W[(size_t)(k0 + wkk0) * EMB + n0 + wnq];
        float4 wv1 = *(const float4*)&W[(size_t)(k0 + wkk0 + 8) * EMB + n0 + wnq];
        __syncthreads();
        {
            float xa0[4] = {xv0.x, xv0.y, xv0.z, xv0.w};
            float xa1[4] = {xv1.x, xv1.y, xv1.z, xv1.w};
#pragma unroll
            for (int j = 0; j < 4; ++j) {
                Xs[xkq + j][xr0]      = xa0[j];
                Xs[xkq + j][xr0 + 64] = xa1[j];
            }
            *(float4*)&Ws[wkk0][wnq]     = wv0;
            *(float4*)&Ws[wkk0 + 8][wnq] = wv1;
        }
        __syncthreads();
#pragma unroll
        for (int kk = 0; kk < 16; ++kk) {
            float a[8], b[8];
            *(float4*)&a[0] = *(const float4*)&Xs[kk][ty * 8];
            *(float4*)&a[4] = *(const float4*)&Xs[kk][ty * 8 + 4];
            *(float4*)&b[0] = *(const float4*)&Ws[kk][tx * 8];
            *(float4*)&b[4] = *(const float4*)&Ws[kk][tx * 8 + 4];
#pragma unroll
            for (int i = 0; i < 8; ++i)
#pragma unroll
                for (int j = 0; j < 8; ++j)
                    acc[i][j] = fmaf(a[i], b[j], acc[i][j]);
        }
    }

    const int nb0 = n0 + tx * 8;
    float4 bv0 = *(const float4*)&bias[nb0];
    float4 bv1 = *(const float4*)&bias[nb0 + 4];
#pragma unroll
    for (int i = 0; i < 8; ++i) {
        const int m = m0 + ty * 8 + i;
        float* dst = &Out[(size_t)m * EMB + nb0];
        *(float4*)&dst[0] = make_float4(acc[i][0] + bv0.x, acc[i][1] + bv0.y,
                                        acc[i][2] + bv0.z, acc[i][3] + bv0.w);
        *(float4*)&dst[4] = make_float4(acc[i][4] + bv1.x, acc[i][5] + bv1.y,
                                        acc[i][6] + bv1.z, acc[i][7] + bv1.w);
    }
}

// ============================================================================
// Pass 1: global min of the FULL (pre-mask) QK^T tensor.
// 128x128 score tile per block, GEMM pattern over d (8 chunks of 16).
// ============================================================================

__global__ __launch_bounds__(256) void qk_min_kernel(
    const float* __restrict__ Q, const float* __restrict__ K,
    float* __restrict__ blockmin)
{
    __shared__ __attribute__((aligned(16))) float Qs[16][132];
    __shared__ __attribute__((aligned(16))) float Ks[16][132];
    __shared__ float sm[256];
    const int t = threadIdx.x;
    const int tx = t & 15, ty = t >> 4;
    const int kt = blockIdx.x, qt = blockIdx.y, bh = blockIdx.z;
    const float* __restrict__ qb = Q + ((size_t)bh * S_LEN + qt * 128) * HD;
    const float* __restrict__ kb = K + ((size_t)bh * S_LEN + kt * 128) * HD;

    const int r0 = t >> 2;
    const int dq = (t & 3) << 2;

    float acc[8][8] = {};

    for (int d0 = 0; d0 < HD; d0 += 16) {
        float4 q0 = *(const float4*)&qb[(size_t)r0 * HD + d0 + dq];
        float4 q1 = *(const float4*)&qb[(size_t)(r0 + 64) * HD + d0 + dq];
        float4 k0 = *(const float4*)&kb[(size_t)r0 * HD + d0 + dq];
        float4 k1 = *(const float4*)&kb[(size_t)(r0 + 64) * HD + d0 + dq];
        __syncthreads();
        {
            float qa0[4] = {q0.x, q0.y, q0.z, q0.w};
            float qa1[4] = {q1.x, q1.y, q1.z, q1.w};
            float ka0[4] = {k0.x, k0.y, k0.z, k0.w};
            float ka1[4] = {k1.x, k1.y, k1.z, k1.w};
#pragma unroll
            for (int j = 0; j < 4; ++j) {
                Qs[dq + j][r0]      = qa0[j];
                Qs[dq + j][r0 + 64] = qa1[j];
                Ks[dq + j][r0]      = ka0[j];
                Ks[dq + j][r0 + 64] = ka1[j];
            }
        }
        __syncthreads();
#pragma unroll
        for (int dk = 0; dk < 16; ++dk) {
            float a[8], b[8];
            *(float4*)&a[0] = *(const float4*)&Qs[dk][ty * 8];
            *(float4*)&a[4] = *(const float4*)&Qs[dk][ty * 8 + 4];
            *(float4*)&b[0] = *(const float4*)&Ks[dk][tx * 8];
            *(float4*)&b[4] = *(const float4*)&Ks[dk][tx * 8 + 4];
#pragma unroll
            for (int i = 0; i < 8; ++i)
#pragma unroll
                for (int j = 0; j < 8; ++j)
                    acc[i][j] = fmaf(a[i], b[j], acc[i][j]);
        }
    }

    float mn = acc[0][0];
#pragma unroll
    for (int i = 0; i < 8; ++i)
#pragma unroll
        for (int j = 0; j < 8; ++j)
            mn = fminf(mn, acc[i][j]);
    sm[t] = mn;
    __syncthreads();
    for (int sft = 128; sft > 0; sft >>= 1) {
        if (t < sft) sm[t] = fminf(sm[t], sm[t + sft]);
        __syncthreads();
    }
    if (t == 0) blockmin[((size_t)bh * 16 + qt) * 16 + kt] = sm[0];
}

__global__ __launch_bounds__(256) void reduce_min_kernel(
    const float* __restrict__ bm, float* __restrict__ minval)
{
    __shared__ float sm[256];
    const int t = threadIdx.x;
    float m = 3.0e38f;
    for (int i = t; i < 16 * 16 * NBH; i += 256) m = fminf(m, bm[i]);
    sm[t] = m;
    __syncthreads();
    for (int sft = 128; sft > 0; sft >>= 1) {
        if (t < sft) sm[t] = fminf(sm[t], sm[t + sft]);
        __syncthreads();
    }
    if (t == 0) minval[0] = sm[0];
}

// ============================================================================
// Suffix sums of V along the sequence: vsuf[bh][i][d] = sum_{j>i} v[bh][j][d]
// 3-phase chunked scan (chunks of 64 rows).
// ============================================================================

__global__ __launch_bounds__(128) void vchunk_sum_kernel(
    const float* __restrict__ V, float* __restrict__ csum)
{
    const int chunk = blockIdx.x, bh = blockIdx.y, d = threadIdx.x;
    const float* vb = V + ((size_t)bh * S_LEN + chunk * 64) * HD + d;
    float s = 0.0f;
    for (int r = 0; r < 64; ++r) s += vb[(size_t)r * HD];
    csum[((size_t)bh * 32 + chunk) * HD + d] = s;
}

__global__ __launch_bounds__(128) void vchunk_suffix_kernel(
    const float* __restrict__ csum, float* __restrict__ csuf)
{
    const int bh = blockIdx.x, d = threadIdx.x;
    float run = 0.0f;
    for (int c = 31; c >= 0; --c) {
        const size_t idx = ((size_t)bh * 32 + c) * HD + d;
        csuf[idx] = run;
        run += csum[idx];
    }
}

__global__ __launch_bounds__(128) void vsuffix_kernel(
    const float* __restrict__ V, const float* __restrict__ csuf,
    float* __restrict__ vsuf)
{
    const int chunk = blockIdx.x, bh = blockIdx.y, d = threadIdx.x;
    float run = csuf[((size_t)bh * 32 + chunk) * HD + d];
    const size_t base = ((size_t)bh * S_LEN + chunk * 64) * HD + d;
    for (int r = 63; r >= 0; --r) {
        vsuf[base + (size_t)r * HD] = run;
        run += V[base + (size_t)r * HD];
    }
}

// ============================================================================
// Pass 2: causal attention with analytic masked correction.
// Block = 64 q rows of one (b,h). K/V subtiles of 32 rows share one LDS buf.
//   out_i = (sum_{j<=i} e^{s_ij} v_j + e^{m*} * suffv_i)
//         / (sum_{j<=i} e^{s_ij} + (S-1-i) e^{m*})
// Output written in merged [B,S,H*D] layout for the final GEMM.
// ============================================================================

__global__ __launch_bounds__(256) void attn_kernel(
    const float* __restrict__ Q, const float* __restrict__ K,
    const float* __restrict__ V, const float* __restrict__ vsuf,
    const float* __restrict__ minval, float* __restrict__ outm)
{
    __shared__ __attribute__((aligned(16))) float Qs[64][132];
    __shared__ __attribute__((aligned(16))) float KVs[32][132];
    __shared__ float Ps[64][33];
    __shared__ float den_l[64];
    const int t = threadIdx.x;
    const int tx = t & 15, ty = t >> 4;
    const int qt = blockIdx.x, bh = blockIdx.y;
    const int b = bh >> 4, h = bh & 15;
    const int i0 = qt * 64;
    const float* __restrict__ qb = Q + ((size_t)bh * S_LEN + i0) * HD;
    const float* __restrict__ kb = K + (size_t)bh * S_LEN * HD;
    const float* __restrict__ vb = V + (size_t)bh * S_LEN * HD;

    // load Q tile [64][128]
#pragma unroll
    for (int i = 0; i < 8; ++i) {
        const int fid = t + i * 256;
        const int r = fid >> 5, c = (fid & 31) << 2;
        *(float4*)&Qs[r][c] = *(const float4*)&qb[(size_t)r * HD + c];
    }

    float acc[4][8] = {};
    float den = 0.0f;  // meaningful on t < 64 (row t)
    const int nst = 2 * (qt + 1);

    for (int st = 0; st < nst; ++st) {
        const int kb0 = st * 32;
        const bool diag = (st >= 2 * qt);

        __syncthreads();  // prior PV reads of KVs/Ps done
        // stage K subtile
#pragma unroll
        for (int i = 0; i < 4; ++i) {
            const int fid = t + i * 256;
            const int r = fid >> 5, c = (fid & 31) << 2;
            *(float4*)&KVs[r][c] = *(const float4*)&kb[(size_t)(kb0 + r) * HD + c];
        }
        __syncthreads();

        // scores: rows ty+16*ii, cols tx+16*jj (strided for bank spread)
        float sacc[4][2] = {};
        for (int d = 0; d < HD; d += 4) {
            float4 qv[4], kv[2];
#pragma unroll
            for (int ii = 0; ii < 4; ++ii)
                qv[ii] = *(const float4*)&Qs[ty + 16 * ii][d];
#pragma unroll
            for (int jj = 0; jj < 2; ++jj)
                kv[jj] = *(const float4*)&KVs[tx + 16 * jj][d];
#pragma unroll
            for (int ii = 0; ii < 4; ++ii)
#pragma unroll
                for (int jj = 0; jj < 2; ++jj) {
                    sacc[ii][jj] = fmaf(qv[ii].x, kv[jj].x, sacc[ii][jj]);
                    sacc[ii][jj] = fmaf(qv[ii].y, kv[jj].y, sacc[ii][jj]);
                    sacc[ii][jj] = fmaf(qv[ii].z, kv[jj].z, sacc[ii][jj]);
                    sacc[ii][jj] = fmaf(qv[ii].w, kv[jj].w, sacc[ii][jj]);
                }
        }
        // exp, causal zero (masked handled analytically), store P
#pragma unroll
        for (int ii = 0; ii < 4; ++ii) {
            const int r = ty + 16 * ii;
            const int ig = i0 + r;
#pragma unroll
            for (int jj = 0; jj < 2; ++jj) {
                const int c = tx + 16 * jj;
                const int jg = kb0 + c;
                float e = __expf(sacc[ii][jj]);
                if (diag && jg > ig) e = 0.0f;
                Ps[r][c] = e;
            }
        }
        __syncthreads();  // scores done -> KVs reusable; Ps visible

        // stage V subtile into the same buffer
#pragma unroll
        for (int i = 0; i < 4; ++i) {
            const int fid = t + i * 256;
            const int r = fid >> 5, c = (fid & 31) << 2;
            *(float4*)&KVs[r][c] = *(const float4*)&vb[(size_t)(kb0 + r) * HD + c];
        }
        // row sums of P (denominator partial), one thread per row
        if (t < 64) {
            float s = 0.0f;
#pragma unroll
            for (int j = 0; j < 32; ++j) s += Ps[t][j];
            den += s;
        }
        __syncthreads();

        // PV accumulate: rows ty*4+ii, cols tx*8..+7
        for (int j = 0; j < 32; ++j) {
            const float4 v0 = *(const float4*)&KVs[j][tx * 8];
            const float4 v1 = *(const float4*)&KVs[j][tx * 8 + 4];
            float p[4];
#pragma unroll
            for (int ii = 0; ii < 4; ++ii) p[ii] = Ps[ty * 4 + ii][j];
#pragma unroll
            for (int ii = 0; ii < 4; ++ii) {
                acc[ii][0] = fmaf(p[ii], v0.x, acc[ii][0]);
                acc[ii][1] = fmaf(p[ii], v0.y, acc[ii][1]);
                acc[ii][2] = fmaf(p[ii], v0.z, acc[ii][2]);
                acc[ii][3] = fmaf(p[ii], v0.w, acc[ii][3]);
                acc[ii][4] = fmaf(p[ii], v1.x, acc[ii][4]);
                acc[ii][5] = fmaf(p[ii], v1.y, acc[ii][5]);
                acc[ii][6] = fmaf(p[ii], v1.z, acc[ii][6]);
                acc[ii][7] = fmaf(p[ii], v1.w, acc[ii][7]);
            }
        }
    }

    __syncthreads();
    if (t < 64) den_l[t] = den;
    __syncthreads();

    const float em = __expf(minval[0]);
#pragma unroll
    for (int ii = 0; ii < 4; ++ii) {
        const int r = ty * 4 + ii;
        const int ig = i0 + r;
        const float dtot = den_l[r] + (float)(S_LEN - 1 - ig) * em;
        const float inv = 1.0f / dtot;
        const float* vs = &vsuf[((size_t)bh * S_LEN + ig) * HD + tx * 8];
        const float4 s0 = *(const float4*)&vs[0];
        const float4 s1 = *(const float4*)&vs[4];
        float4 o0, o1;
        o0.x = (acc[ii][0] + em * s0.x) * inv;
        o0.y = (acc[ii][1] + em * s0.y) * inv;
        o0.z = (acc[ii][2] + em * s0.z) * inv;
        o0.w = (acc[ii][3] + em * s0.w) * inv;
        o1.x = (acc[ii][4] + em * s1.x) * inv;
        o1.y = (acc[ii][5] + em * s1.y) * inv;
        o1.z = (acc[ii][6] + em * s1.z) * inv;
        o1.w = (acc[ii][7] + em * s1.w) * inv;
        const size_t oo = (((size_t)b * S_LEN + ig) * NH + h) * HD + tx * 8;
        *(float4*)&outm[oo]     = o0;
        *(float4*)&outm[oo + 4] = o1;
    }
}

// ============================================================================
// Launch
// ============================================================================

extern "C" void kernel_launch(void* const* d_in, const int* in_sizes, int n_in,
                              void* d_out, int out_size, void* d_ws, size_t ws_size,
                              hipStream_t stream)
{
    const float* hs = (const float*)d_in[0];
    const float* wq = (const float*)d_in[1];
    const float* wk = (const float*)d_in[2];
    const float* wv = (const float*)d_in[3];
    const float* wo = (const float*)d_in[4];
    const float* bo = (const float*)d_in[5];
    float* out = (float*)d_out;

    float* ws = (float*)d_ws;
    const size_t SZ = (size_t)NBH * S_LEN * HD;  // 8388608 elems per tensor
    float* Qb       = ws;
    float* Kb       = Qb + SZ;
    float* Vb       = Kb + SZ;
    float* vsuf     = Vb + SZ;
    float* outm     = vsuf + SZ;
    float* csum     = outm + SZ;                       // NBH*32*HD = 131072
    float* csuf     = csum + (size_t)NBH * 32 * HD;
    float* blockmin = csuf + (size_t)NBH * 32 * HD;    // 8192
    float* minval   = blockmin + 8192;
    // total: 5*8388608 + 2*131072 + 8192 + 64 floats ~= 169 MB

    gemm_qkv_kernel<<<dim3(EMB / 128, MTOT / 128, 3), 256, 0, stream>>>(
        hs, wq, wk, wv, Qb, Kb, Vb);

    vchunk_sum_kernel<<<dim3(32, NBH), 128, 0, stream>>>(Vb, csum);
    vchunk_suffix_kernel<<<NBH, 128, 0, stream>>>(csum, csuf);
    vsuffix_kernel<<<dim3(32, NBH), 128, 0, stream>>>(Vb, csuf, vsuf);

    qk_min_kernel<<<dim3(16, 16, NBH), 256, 0, stream>>>(Qb, Kb, blockmin);
    reduce_min_kernel<<<1, 256, 0, stream>>>(blockmin, minval);

    attn_kernel<<<dim3(S_LEN / 64, NBH), 256, 0, stream>>>(
        Qb, Kb, Vb, vsuf, minval, outm);

    gemm_out_kernel<<<dim3(EMB / 128, MTOT / 128), 256, 0, stream>>>(
        outm, wo, bo, out);
}

// Round 2
// 482.629 us; speedup vs baseline: 6.7160x; 6.7160x over previous
//
#include <hip/hip_runtime.h>

typedef unsigned short u16;
typedef unsigned int   u32;
typedef __attribute__((ext_vector_type(4))) float f32x4;
typedef __attribute__((ext_vector_type(4))) u32   u32x4;
typedef __attribute__((ext_vector_type(8))) __bf16 bf16x8;

#define S_LEN 2048
#define EMB   2048
#define NH    16
#define HD    128
#define NBH   32
#define MTOT  4096

__device__ __forceinline__ u16 f2bf(float f) {
    u32 u = __float_as_uint(f);
    return (u16)((u + 0x7FFFu + ((u >> 16) & 1u)) >> 16);
}
__device__ __forceinline__ float bf2f(u16 v) {
    return __uint_as_float(((u32)v) << 16);
}
__device__ __forceinline__ bf16x8 ld_frag(const u16* p) {
    return __builtin_bit_cast(bf16x8, *(const u32x4*)p);
}
// async global->LDS, 16B per lane; LDS dest = wave-uniform base + lane*16
__device__ __forceinline__ void gld_lds16(const void* g, void* l) {
    __builtin_amdgcn_global_load_lds(
        (__attribute__((address_space(1))) void*)(g),
        (__attribute__((address_space(3))) void*)(l), 16, 0, 0);
}

// ============================================================================
// cast X fp32 -> bf16
// ============================================================================
__global__ __launch_bounds__(256) void cast_x_kernel(
    const float* __restrict__ X, u16* __restrict__ Xb)
{
    const size_t i = ((size_t)blockIdx.x * 256 + threadIdx.x) * 8;
    float4 a = *(const float4*)&X[i];
    float4 b = *(const float4*)&X[i + 4];
    u32x4 o;
    o.x = (u32)f2bf(a.x) | ((u32)f2bf(a.y) << 16);
    o.y = (u32)f2bf(a.z) | ((u32)f2bf(a.w) << 16);
    o.z = (u32)f2bf(b.x) | ((u32)f2bf(b.y) << 16);
    o.w = (u32)f2bf(b.z) | ((u32)f2bf(b.w) << 16);
    *(u32x4*)&Xb[i] = o;
}

// ============================================================================
// transpose-cast weights: W [K][N] fp32 -> Wt [N][K] bf16 (B^T operand form)
// ============================================================================
__global__ __launch_bounds__(256) void transpose_cast_w_kernel(
    const float* __restrict__ W0, const float* __restrict__ W1,
    const float* __restrict__ W2, const float* __restrict__ W3,
    u16* __restrict__ T0, u16* __restrict__ T1,
    u16* __restrict__ T2, u16* __restrict__ T3)
{
    __shared__ float Ls[64][68];
    const int t = threadIdx.x;
    const int n0 = blockIdx.x * 64, k0 = blockIdx.y * 64;
    const int z = blockIdx.z;
    const float* __restrict__ W = (z == 0) ? W0 : (z == 1) ? W1 : (z == 2) ? W2 : W3;
    u16* __restrict__ T = (z == 0) ? T0 : (z == 1) ? T1 : (z == 2) ? T2 : T3;

#pragma unroll
    for (int p = 0; p < 4; ++p) {
        const int r = (t >> 4) + 16 * p;
        const int c = (t & 15) * 4;
        *(float4*)&Ls[r][c] = *(const float4*)&W[(size_t)(k0 + r) * EMB + n0 + c];
    }
    __syncthreads();
    const int nl = t >> 2, q = t & 3;
    u32 pk[8];
#pragma unroll
    for (int j = 0; j < 8; ++j) {
        u16 lo = f2bf(Ls[q * 16 + 2 * j][nl]);
        u16 hi = f2bf(Ls[q * 16 + 2 * j + 1][nl]);
        pk[j] = (u32)lo | ((u32)hi << 16);
    }
    u32x4 o0 = {pk[0], pk[1], pk[2], pk[3]};
    u32x4 o1 = {pk[4], pk[5], pk[6], pk[7]};
    u16* dst = &T[(size_t)(n0 + nl) * EMB + k0 + q * 16];
    *(u32x4*)&dst[0] = o0;
    *(u32x4*)&dst[8] = o1;
}

// ============================================================================
// transpose V bf16 [bh][s][d] -> Vt [bh][d][s]
// ============================================================================
__global__ __launch_bounds__(256) void transpose_v_kernel(
    const u16* __restrict__ V, u16* __restrict__ Vt)
{
    __shared__ u16 Ls[64][72];
    const int t = threadIdx.x;
    const int s0 = blockIdx.x * 64, d0 = blockIdx.y * 64, bh = blockIdx.z;
    const u16* __restrict__ src0 = V + ((size_t)bh * S_LEN) * HD;
    {
        const int r = t >> 2, c0 = (t & 3) * 16;
        const u16* src = &src0[(size_t)(s0 + r) * HD + d0 + c0];
        *(u32x4*)&Ls[r][c0]     = *(const u32x4*)&src[0];
        *(u32x4*)&Ls[r][c0 + 8] = *(const u32x4*)&src[8];
    }
    __syncthreads();
    const int dl = t >> 2, q = t & 3;
    u32 pk[8];
#pragma unroll
    for (int j = 0; j < 8; ++j) {
        u16 lo = Ls[q * 16 + 2 * j][dl];
        u16 hi = Ls[q * 16 + 2 * j + 1][dl];
        pk[j] = (u32)lo | ((u32)hi << 16);
    }
    u32x4 o0 = {pk[0], pk[1], pk[2], pk[3]};
    u32x4 o1 = {pk[4], pk[5], pk[6], pk[7]};
    u16* dst = &Vt[((size_t)bh * HD + d0 + dl) * S_LEN + s0 + q * 16];
    *(u32x4*)&dst[0] = o0;
    *(u32x4*)&dst[8] = o1;
}

// ============================================================================
// bf16 MFMA GEMM, m97 pattern: 128x128 tile, BK=32, 4 waves (2x2), each wave
// 4x4 of 16x16x32 MFMAs. A [M][K] bf16, B^T [N][K] bf16.
// qkv variant: 3 weights via blockIdx.z, epilogue scatters to [bh][s][d].
// ============================================================================
__global__ __launch_bounds__(256) void gemm_qkv_mfma(
    const u16* __restrict__ Xb,
    const u16* __restrict__ Wtq, const u16* __restrict__ Wtk,
    const u16* __restrict__ Wtv,
    u16* __restrict__ Qo, u16* __restrict__ Ko, u16* __restrict__ Vo)
{
    __shared__ __attribute__((aligned(16))) u16 As[128 * 32];
    __shared__ __attribute__((aligned(16))) u16 Bs[128 * 32];
    const int t = threadIdx.x;
    const int w = t >> 6, lane = t & 63;
    const int wy = w >> 1, wx = w & 1;
    const int n0 = blockIdx.x * 128, m0 = blockIdx.y * 128;
    const int z = blockIdx.z;
    const u16* __restrict__ Wt = (z == 0) ? Wtq : (z == 1) ? Wtk : Wtv;
    u16* __restrict__ O = (z == 0) ? Qo : (z == 1) ? Ko : Vo;

    const int srow = lane >> 2, scol = (lane & 3) * 8;
    const u16* Ag = &Xb[(size_t)(m0 + w * 32 + srow) * EMB + scol];
    const u16* Bg = &Wt[(size_t)(n0 + w * 32 + srow) * EMB + scol];
    u16* Al0 = &As[(w * 32) * 32];
    u16* Al1 = &As[(w * 32 + 16) * 32];
    u16* Bl0 = &Bs[(w * 32) * 32];
    u16* Bl1 = &Bs[(w * 32 + 16) * 32];

    const int fm = lane & 15, fk = (lane >> 4) * 8;
    f32x4 acc[4][4];
#pragma unroll
    for (int i = 0; i < 4; ++i)
#pragma unroll
        for (int j = 0; j < 4; ++j) acc[i][j] = (f32x4)0.0f;

    for (int k0 = 0; k0 < EMB; k0 += 32) {
        __syncthreads();
        gld_lds16(Ag + k0, Al0);
        gld_lds16(Ag + 16 * EMB + k0, Al1);
        gld_lds16(Bg + k0, Bl0);
        gld_lds16(Bg + 16 * EMB + k0, Bl1);
        __syncthreads();
        bf16x8 af[4], bfr[4];
#pragma unroll
        for (int mi = 0; mi < 4; ++mi)
            af[mi] = ld_frag(&As[(64 * wy + 16 * mi + fm) * 32 + fk]);
#pragma unroll
        for (int ni = 0; ni < 4; ++ni)
            bfr[ni] = ld_frag(&Bs[(64 * wx + 16 * ni + fm) * 32 + fk]);
#pragma unroll
        for (int mi = 0; mi < 4; ++mi)
#pragma unroll
            for (int ni = 0; ni < 4; ++ni)
                acc[mi][ni] = __builtin_amdgcn_mfma_f32_16x16x32_bf16(
                    af[mi], bfr[ni], acc[mi][ni], 0, 0, 0);
    }

    const int q4 = (lane >> 4) * 4;
#pragma unroll
    for (int mi = 0; mi < 4; ++mi)
#pragma unroll
        for (int ni = 0; ni < 4; ++ni) {
            const int n = n0 + 64 * wx + 16 * ni + (lane & 15);
            const int h = n >> 7, d = n & 127;
#pragma unroll
            for (int r = 0; r < 4; ++r) {
                const int m = m0 + 64 * wy + 16 * mi + q4 + r;
                const int bb = m >> 11, s = m & 2047;
                O[(((size_t)(bb * NH + h) * S_LEN) + s) * HD + d] = f2bf(acc[mi][ni][r]);
            }
        }
}

__global__ __launch_bounds__(256) void gemm_out_mfma(
    const u16* __restrict__ Ab, const u16* __restrict__ Wto,
    const float* __restrict__ bias, float* __restrict__ Out)
{
    __shared__ __attribute__((aligned(16))) u16 As[128 * 32];
    __shared__ __attribute__((aligned(16))) u16 Bs[128 * 32];
    const int t = threadIdx.x;
    const int w = t >> 6, lane = t & 63;
    const int wy = w >> 1, wx = w & 1;
    const int n0 = blockIdx.x * 128, m0 = blockIdx.y * 128;

    const int srow = lane >> 2, scol = (lane & 3) * 8;
    const u16* Ag = &Ab[(size_t)(m0 + w * 32 + srow) * EMB + scol];
    const u16* Bg = &Wto[(size_t)(n0 + w * 32 + srow) * EMB + scol];
    u16* Al0 = &As[(w * 32) * 32];
    u16* Al1 = &As[(w * 32 + 16) * 32];
    u16* Bl0 = &Bs[(w * 32) * 32];
    u16* Bl1 = &Bs[(w * 32 + 16) * 32];

    const int fm = lane & 15, fk = (lane >> 4) * 8;
    f32x4 acc[4][4];
#pragma unroll
    for (int i = 0; i < 4; ++i)
#pragma unroll
        for (int j = 0; j < 4; ++j) acc[i][j] = (f32x4)0.0f;

    for (int k0 = 0; k0 < EMB; k0 += 32) {
        __syncthreads();
        gld_lds16(Ag + k0, Al0);
        gld_lds16(Ag + 16 * EMB + k0, Al1);
        gld_lds16(Bg + k0, Bl0);
        gld_lds16(Bg + 16 * EMB + k0, Bl1);
        __syncthreads();
        bf16x8 af[4], bfr[4];
#pragma unroll
        for (int mi = 0; mi < 4; ++mi)
            af[mi] = ld_frag(&As[(64 * wy + 16 * mi + fm) * 32 + fk]);
#pragma unroll
        for (int ni = 0; ni < 4; ++ni)
            bfr[ni] = ld_frag(&Bs[(64 * wx + 16 * ni + fm) * 32 + fk]);
#pragma unroll
        for (int mi = 0; mi < 4; ++mi)
#pragma unroll
            for (int ni = 0; ni < 4; ++ni)
                acc[mi][ni] = __builtin_amdgcn_mfma_f32_16x16x32_bf16(
                    af[mi], bfr[ni], acc[mi][ni], 0, 0, 0);
    }

    const int q4 = (lane >> 4) * 4;
#pragma unroll
    for (int mi = 0; mi < 4; ++mi)
#pragma unroll
        for (int ni = 0; ni < 4; ++ni) {
            const int n = n0 + 64 * wx + 16 * ni + (lane & 15);
            const float bv = bias[n];
#pragma unroll
            for (int r = 0; r < 4; ++r) {
                const int m = m0 + 64 * wy + 16 * mi + q4 + r;
                Out[(size_t)m * EMB + n] = acc[mi][ni][r] + bv;
            }
        }
}

// ============================================================================
// Global min of full (pre-mask) QK^T — MFMA GEMM with min-reduce epilogue.
// ============================================================================
__global__ __launch_bounds__(256) void qk_min_mfma(
    const u16* __restrict__ Q, const u16* __restrict__ K,
    float* __restrict__ blockmin)
{
    __shared__ __attribute__((aligned(16))) u16 As[128 * 32];
    __shared__ __attribute__((aligned(16))) u16 Bs[128 * 32];
    __shared__ float sm[256];
    const int t = threadIdx.x;
    const int w = t >> 6, lane = t & 63;
    const int wy = w >> 1, wx = w & 1;
    const int kt = blockIdx.x, qt = blockIdx.y, bh = blockIdx.z;

    const int srow = lane >> 2, scol = (lane & 3) * 8;
    const u16* Ag = &Q[((size_t)bh * S_LEN + qt * 128 + w * 32 + srow) * HD + scol];
    const u16* Bg = &K[((size_t)bh * S_LEN + kt * 128 + w * 32 + srow) * HD + scol];
    u16* Al0 = &As[(w * 32) * 32];
    u16* Al1 = &As[(w * 32 + 16) * 32];
    u16* Bl0 = &Bs[(w * 32) * 32];
    u16* Bl1 = &Bs[(w * 32 + 16) * 32];

    const int fm = lane & 15, fk = (lane >> 4) * 8;
    f32x4 acc[4][4];
#pragma unroll
    for (int i = 0; i < 4; ++i)
#pragma unroll
        for (int j = 0; j < 4; ++j) acc[i][j] = (f32x4)0.0f;

    for (int k0 = 0; k0 < HD; k0 += 32) {
        __syncthreads();
        gld_lds16(Ag + k0, Al0);
        gld_lds16(Ag + 16 * HD + k0, Al1);
        gld_lds16(Bg + k0, Bl0);
        gld_lds16(Bg + 16 * HD + k0, Bl1);
        __syncthreads();
        bf16x8 af[4], bfr[4];
#pragma unroll
        for (int mi = 0; mi < 4; ++mi)
            af[mi] = ld_frag(&As[(64 * wy + 16 * mi + fm) * 32 + fk]);
#pragma unroll
        for (int ni = 0; ni < 4; ++ni)
            bfr[ni] = ld_frag(&Bs[(64 * wx + 16 * ni + fm) * 32 + fk]);
#pragma unroll
        for (int mi = 0; mi < 4; ++mi)
#pragma unroll
            for (int ni = 0; ni < 4; ++ni)
                acc[mi][ni] = __builtin_amdgcn_mfma_f32_16x16x32_bf16(
                    af[mi], bfr[ni], acc[mi][ni], 0, 0, 0);
    }

    float mn = acc[0][0][0];
#pragma unroll
    for (int mi = 0; mi < 4; ++mi)
#pragma unroll
        for (int ni = 0; ni < 4; ++ni)
#pragma unroll
            for (int r = 0; r < 4; ++r) mn = fminf(mn, acc[mi][ni][r]);
    sm[t] = mn;
    __syncthreads();
    for (int sft = 128; sft > 0; sft >>= 1) {
        if (t < sft) sm[t] = fminf(sm[t], sm[t + sft]);
        __syncthreads();
    }
    if (t == 0) blockmin[((size_t)bh * 16 + qt) * 16 + kt] = sm[0];
}

__global__ __launch_bounds__(256) void reduce_min_kernel(
    const float* __restrict__ bm, float* __restrict__ minval)
{
    __shared__ float sm[256];
    const int t = threadIdx.x;
    float m = 3.0e38f;
    for (int i = t; i < 16 * 16 * NBH; i += 256) m = fminf(m, bm[i]);
    sm[t] = m;
    __syncthreads();
    for (int sft = 128; sft > 0; sft >>= 1) {
        if (t < sft) sm[t] = fminf(sm[t], sm[t + sft]);
        __syncthreads();
    }
    if (t == 0) minval[0] = sm[0];
}

// ============================================================================
// V suffix sums (bf16 in, fp32 out): vsuf[bh][i][d] = sum_{j>i} v[bh][j][d]
// ============================================================================
__global__ __launch_bounds__(128) void vchunk_sum_kernel(
    const u16* __restrict__ V, float* __restrict__ csum)
{
    const int chunk = blockIdx.x, bh = blockIdx.y, d = threadIdx.x;
    const u16* vb = V + ((size_t)bh * S_LEN + chunk * 64) * HD + d;
    float s = 0.0f;
    for (int r = 0; r < 64; ++r) s += bf2f(vb[(size_t)r * HD]);
    csum[((size_t)bh * 32 + chunk) * HD + d] = s;
}

__global__ __launch_bounds__(128) void vchunk_suffix_kernel(
    const float* __restrict__ csum, float* __restrict__ csuf)
{
    const int bh = blockIdx.x, d = threadIdx.x;
    float run = 0.0f;
    for (int c = 31; c >= 0; --c) {
        const size_t idx = ((size_t)bh * 32 + c) * HD + d;
        csuf[idx] = run;
        run += csum[idx];
    }
}

__global__ __launch_bounds__(128) void vsuffix_kernel(
    const u16* __restrict__ V, const float* __restrict__ csuf,
    float* __restrict__ vsuf)
{
    const int chunk = blockIdx.x, bh = blockIdx.y, d = threadIdx.x;
    float run = csuf[((size_t)bh * 32 + chunk) * HD + d];
    const size_t base = ((size_t)bh * S_LEN + chunk * 64) * HD + d;
    for (int r = 63; r >= 0; --r) {
        vsuf[base + (size_t)r * HD] = run;
        run += bf2f(V[base + (size_t)r * HD]);
    }
}

// ============================================================================
// Flash-style causal attention, bf16 MFMA, analytic masked correction.
// 128 q-rows per block; K-tiles of 128 processed in BK=32 MFMA chunks.
// Qs/Ps padded to 136 u16/row (272B = 17*16B) -> 2-way (free) LDS reads.
// ============================================================================
__global__ __launch_bounds__(256) void attn_mfma(
    const u16* __restrict__ Q, const u16* __restrict__ K,
    const u16* __restrict__ Vt, const float* __restrict__ vsuf,
    const float* __restrict__ minval, u16* __restrict__ outm)
{
    __shared__ __attribute__((aligned(16))) u16 Qs[128 * 136];
    __shared__ __attribute__((aligned(16))) u16 Ps[128 * 136];
    __shared__ __attribute__((aligned(16))) u16 Cs[128 * 32];
    __shared__ float den_l[2][128];

    const int t = threadIdx.x;
    const int w = t >> 6, lane = t & 63;
    const int wy = w >> 1, wx = w & 1;
    const int qt = blockIdx.x, bh = blockIdx.y;
    const int b = bh >> 4, h = bh & 15;
    const int i0 = qt * 128;

    const u16* __restrict__ Qg  = Q + ((size_t)bh * S_LEN + i0) * HD;
    const u16* __restrict__ Kg  = K + (size_t)bh * S_LEN * HD;
    const u16* __restrict__ Vtg = Vt + (size_t)bh * HD * S_LEN;

    // Q tile -> padded LDS
    {
        const int r = t >> 1, ch = (t & 1) * 64;
        const u16* src = &Qg[(size_t)r * HD + ch];
        u16* dst = &Qs[r * 136 + ch];
#pragma unroll
        for (int j = 0; j < 8; ++j)
            *(u32x4*)&dst[j * 8] = *(const u32x4*)&src[j * 8];
    }

    const int srow = lane >> 2, scol = (lane & 3) * 8;
    const int fm = lane & 15, fk = (lane >> 4) * 8;
    const int q4 = (lane >> 4) * 4;

    f32x4 oacc[4][4];
#pragma unroll
    for (int i = 0; i < 4; ++i)
#pragma unroll
        for (int j = 0; j < 4; ++j) oacc[i][j] = (f32x4)0.0f;
    float den[4][4] = {};

    const int ntile = qt + 1;
    for (int jt = 0; jt < ntile; ++jt) {
        const int j0 = jt * 128;
        // ---- S = Q K^T ----
        f32x4 sacc[4][4];
#pragma unroll
        for (int i = 0; i < 4; ++i)
#pragma unroll
            for (int j = 0; j < 4; ++j) sacc[i][j] = (f32x4)0.0f;
        for (int dk = 0; dk < 4; ++dk) {
            __syncthreads();
            {
                const u16* g = &Kg[(size_t)(j0 + w * 32 + srow) * HD + dk * 32 + scol];
                gld_lds16(g, &Cs[(w * 32) * 32]);
                gld_lds16(g + 16 * HD, &Cs[(w * 32 + 16) * 32]);
            }
            __syncthreads();
            bf16x8 af[4], bfr[4];
#pragma unroll
            for (int mi = 0; mi < 4; ++mi)
                af[mi] = ld_frag(&Qs[(64 * wy + 16 * mi + fm) * 136 + dk * 32 + fk]);
#pragma unroll
            for (int ni = 0; ni < 4; ++ni)
                bfr[ni] = ld_frag(&Cs[(64 * wx + 16 * ni + fm) * 32 + fk]);
#pragma unroll
            for (int mi = 0; mi < 4; ++mi)
#pragma unroll
                for (int ni = 0; ni < 4; ++ni)
                    sacc[mi][ni] = __builtin_amdgcn_mfma_f32_16x16x32_bf16(
                        af[mi], bfr[ni], sacc[mi][ni], 0, 0, 0);
        }
        // ---- exp epilogue -> Ps (bf16), den (fp32) ----
        const bool dg = (jt == qt);
#pragma unroll
        for (int mi = 0; mi < 4; ++mi) {
            const int rbase = 64 * wy + 16 * mi + q4;
#pragma unroll
            for (int ni = 0; ni < 4; ++ni) {
                const int cl = 64 * wx + 16 * ni + (lane & 15);
                const int jg = j0 + cl;
#pragma unroll
                for (int r = 0; r < 4; ++r) {
                    float e = __expf(sacc[mi][ni][r]);
                    if (dg && jg > i0 + rbase + r) e = 0.0f;
                    den[mi][r] += e;
                    Ps[(rbase + r) * 136 + cl] = f2bf(e);
                }
            }
        }
        // ---- O += P V ----
        for (int sk = 0; sk < 4; ++sk) {
            __syncthreads();
            {
                const u16* g = &Vtg[(size_t)(w * 32 + srow) * S_LEN + j0 + sk * 32 + scol];
                gld_lds16(g, &Cs[(w * 32) * 32]);
                gld_lds16(g + 16 * S_LEN, &Cs[(w * 32 + 16) * 32]);
            }
            __syncthreads();
            bf16x8 pa[4], pb[4];
#pragma unroll
            for (int mi = 0; mi < 4; ++mi)
                pa[mi] = ld_frag(&Ps[(64 * wy + 16 * mi + fm) * 136 + sk * 32 + fk]);
#pragma unroll
            for (int ni = 0; ni < 4; ++ni)
                pb[ni] = ld_frag(&Cs[(64 * wx + 16 * ni + fm) * 32 + fk]);
#pragma unroll
            for (int mi = 0; mi < 4; ++mi)
#pragma unroll
                for (int ni = 0; ni < 4; ++ni)
                    oacc[mi][ni] = __builtin_amdgcn_mfma_f32_16x16x32_bf16(
                        pa[mi], pb[ni], oacc[mi][ni], 0, 0, 0);
        }
    }

    // row-sum reduce across the 16 col-lanes of each quad
#pragma unroll
    for (int mi = 0; mi < 4; ++mi)
#pragma unroll
        for (int r = 0; r < 4; ++r) {
            float v = den[mi][r];
            v += __shfl_xor(v, 1, 64);
            v += __shfl_xor(v, 2, 64);
            v += __shfl_xor(v, 4, 64);
            v += __shfl_xor(v, 8, 64);
            den[mi][r] = v;
        }
    __syncthreads();
    if ((lane & 15) == 0) {
#pragma unroll
        for (int mi = 0; mi < 4; ++mi)
#pragma unroll
            for (int r = 0; r < 4; ++r)
                den_l[wx][64 * wy + 16 * mi + q4 + r] = den[mi][r];
    }
    __syncthreads();

    const float em = __expf(minval[0]);
#pragma unroll
    for (int mi = 0; mi < 4; ++mi)
#pragma unroll
        for (int ni = 0; ni < 4; ++ni) {
            const int d = 64 * wx + 16 * ni + (lane & 15);
#pragma unroll
            for (int r = 0; r < 4; ++r) {
                const int row = 64 * wy + 16 * mi + q4 + r;
                const int ig = i0 + row;
                const float dt = den_l[0][row] + den_l[1][row]
                               + (float)(S_LEN - 1 - ig) * em;
                const float sv = vsuf[((size_t)bh * S_LEN + ig) * HD + d];
                const float o = (oacc[mi][ni][r] + em * sv) / dt;
                outm[((size_t)b * S_LEN + ig) * EMB + h * HD + d] = f2bf(o);
            }
        }
}

// ============================================================================
// Launch
// ============================================================================
extern "C" void kernel_launch(void* const* d_in, const int* in_sizes, int n_in,
                              void* d_out, int out_size, void* d_ws, size_t ws_size,
                              hipStream_t stream)
{
    (void)in_sizes; (void)n_in; (void)out_size; (void)ws_size;
    const float* hs = (const float*)d_in[0];
    const float* wq = (const float*)d_in[1];
    const float* wk = (const float*)d_in[2];
    const float* wv = (const float*)d_in[3];
    const float* wo = (const float*)d_in[4];
    const float* bo = (const float*)d_in[5];
    float* out = (float*)d_out;

    char* p = (char*)d_ws;
    const size_t TS = (size_t)NBH * S_LEN * HD;  // 8388608
    u16* Xb   = (u16*)p; p += (size_t)MTOT * EMB * 2;
    u16* Wtq  = (u16*)p; p += (size_t)EMB * EMB * 2;
    u16* Wtk  = (u16*)p; p += (size_t)EMB * EMB * 2;
    u16* Wtv  = (u16*)p; p += (size_t)EMB * EMB * 2;
    u16* Wto  = (u16*)p; p += (size_t)EMB * EMB * 2;
    u16* Qb   = (u16*)p; p += TS * 2;
    u16* Kb   = (u16*)p; p += TS * 2;
    u16* Vb   = (u16*)p; p += TS * 2;
    u16* Vtb  = (u16*)p; p += TS * 2;
    u16* outm = (u16*)p; p += (size_t)MTOT * EMB * 2;
    float* vsuf     = (float*)p; p += TS * 4;
    float* csum     = (float*)p; p += (size_t)NBH * 32 * HD * 4;
    float* csuf     = (float*)p; p += (size_t)NBH * 32 * HD * 4;
    float* blockmin = (float*)p; p += 8192 * 4;
    float* minval   = (float*)p; p += 64;

    cast_x_kernel<<<4096, 256, 0, stream>>>(hs, Xb);
    transpose_cast_w_kernel<<<dim3(32, 32, 4), 256, 0, stream>>>(
        wq, wk, wv, wo, Wtq, Wtk, Wtv, Wto);

    gemm_qkv_mfma<<<dim3(EMB / 128, MTOT / 128, 3), 256, 0, stream>>>(
        Xb, Wtq, Wtk, Wtv, Qb, Kb, Vb);

    transpose_v_kernel<<<dim3(32, 2, NBH), 256, 0, stream>>>(Vb, Vtb);
    vchunk_sum_kernel<<<dim3(32, NBH), 128, 0, stream>>>(Vb, csum);
    vchunk_suffix_kernel<<<NBH, 128, 0, stream>>>(csum, csuf);
    vsuffix_kernel<<<dim3(32, NBH), 128, 0, stream>>>(Vb, csuf, vsuf);

    qk_min_mfma<<<dim3(16, 16, NBH), 256, 0, stream>>>(Qb, Kb, blockmin);
    reduce_min_kernel<<<1, 256, 0, stream>>>(blockmin, minval);

    attn_mfma<<<dim3(S_LEN / 128, NBH), 256, 0, stream>>>(
        Qb, Kb, Vtb, vsuf, minval, outm);

    gemm_out_mfma<<<dim3(EMB / 128, MTOT / 128), 256, 0, stream>>>(
        outm, Wto, bo, out);
}